// Round 2
// baseline (461.532 us; speedup 1.0000x reference)
//
#include <hip/hip_runtime.h>
#include <cstdint>
#include <cstddef>

#define EPI_QKV  0
#define EPI_F32  2
#define EPI_GELU 3
#define EPI_PART 4

typedef __attribute__((ext_vector_type(8))) short bfrag8;   // 8 bf16 (4 VGPRs)
typedef __attribute__((ext_vector_type(4))) float facc4;    // 4 fp32 acc

struct PtrQuad { unsigned short* p[4]; };

__device__ __forceinline__ unsigned short f2b(float x) {
  unsigned int u = __builtin_bit_cast(unsigned int, x);
  u += 0x7FFFu + ((u >> 16) & 1u);   // RNE
  return (unsigned short)(u >> 16);
}
__device__ __forceinline__ float b2f(unsigned short u) {
  unsigned int x = ((unsigned int)u) << 16;
  return __builtin_bit_cast(float, x);
}

__device__ __forceinline__ void gl2lds16(const unsigned short* g, unsigned short* l) {
  __builtin_amdgcn_global_load_lds(
      (const __attribute__((address_space(1))) unsigned int*)g,
      (__attribute__((address_space(3))) unsigned int*)l, 16, 0, 0);
}

// ---------------- elementwise fp32 -> bf16 ----------------
__global__ __launch_bounds__(256)
void cvt_bf16_kernel(const float* __restrict__ in, unsigned short* __restrict__ out, int n4) {
  const int i = blockIdx.x * 256 + threadIdx.x;
  if (i < n4) {
    const float4 v = ((const float4*)in)[i];
    ushort4 u;
    u.x = f2b(v.x); u.y = f2b(v.y); u.z = f2b(v.z); u.w = f2b(v.w);
    ((ushort4*)out)[i] = u;
  }
}

// ---------------- transpose + convert: in (K x N) fp32 -> out (N x K) bf16 ----------------
__global__ __launch_bounds__(256)
void transpose_cvt(const float* __restrict__ in, unsigned short* __restrict__ out,
                   int K, int N) {
  __shared__ float tile[32][33];
  const int n0 = blockIdx.x * 32;
  const int k0 = blockIdx.y * 32;
  const int tx = threadIdx.x & 31, ty = threadIdx.x >> 5;  // ty 0..7
#pragma unroll
  for (int i = 0; i < 32; i += 8)
    tile[ty + i][tx] = in[(size_t)(k0 + ty + i) * N + n0 + tx];
  __syncthreads();
#pragma unroll
  for (int i = 0; i < 32; i += 8)
    out[(size_t)(n0 + ty + i) * K + k0 + tx] = f2b(tile[tx][ty + i]);
}

// ---------------- GEMM: C = A(MxK') @ Bt(NxK')^T slice, bf16 MFMA, fused epilogues ------
// 128x128 tile, BK=32, 4 waves (2x2), 4x4 16x16x32 MFMA per wave. m97 structure.
template<int EPI>
__global__ __launch_bounds__(256, 2)
void gemm_bt(const unsigned short* __restrict__ A,
             const unsigned short* __restrict__ Bt,
             const float* __restrict__ bias,
             const float* __restrict__ bias2,
             const float* __restrict__ bias3,
             void* __restrict__ out, PtrQuad pq,
             int M, int N, int K, int ldk) {
  __shared__ unsigned short sA[128 * 32];
  __shared__ unsigned short sB[128 * 32];
  const int tid  = threadIdx.x;
  const int lane = tid & 63;
  const int wave = tid >> 6;
  const int l15  = lane & 15, l4 = lane >> 4;
  const int wr = wave >> 1, wc = wave & 1;
  const long row0 = (long)blockIdx.y * 128;
  const long col0 = (long)blockIdx.x * 128;
  const long k0   = (long)blockIdx.z * K;

  facc4 acc[4][4];
#pragma unroll
  for (int i = 0; i < 4; i++)
#pragma unroll
    for (int j = 0; j < 4; j++) acc[i][j] = (facc4)0.f;

  const int srow = tid >> 2;
  const int scol = (tid & 3) * 8;
  const unsigned short* Ap0 = A  + (row0 + srow) * (long)ldk + k0 + scol;
  const unsigned short* Ap1 = Ap0 + 64 * (long)ldk;
  const unsigned short* Bp0 = Bt + (col0 + srow) * (long)ldk + k0 + scol;
  const unsigned short* Bp1 = Bp0 + 64 * (long)ldk;
  const int wbase = (tid & ~63) * 8;
  unsigned short* sA0 = &sA[wbase];
  unsigned short* sA1 = &sA[2048 + wbase];
  unsigned short* sB0 = &sB[wbase];
  unsigned short* sB1 = &sB[2048 + wbase];

  const int aoff = (wr * 64 + l15) * 32 + l4 * 8;
  const int boff = (wc * 64 + l15) * 32 + l4 * 8;

  for (int kt = 0; kt < K; kt += 32) {
    gl2lds16(Ap0 + kt, sA0);
    gl2lds16(Ap1 + kt, sA1);
    gl2lds16(Bp0 + kt, sB0);
    gl2lds16(Bp1 + kt, sB1);
    __syncthreads();
    bfrag8 af[4], bf[4];
#pragma unroll
    for (int i = 0; i < 4; i++) af[i] = *(const bfrag8*)&sA[aoff + i * 512];
#pragma unroll
    for (int j = 0; j < 4; j++) bf[j] = *(const bfrag8*)&sB[boff + j * 512];
#pragma unroll
    for (int i = 0; i < 4; i++)
#pragma unroll
      for (int j = 0; j < 4; j++)
        acc[i][j] = __builtin_amdgcn_mfma_f32_16x16x32_bf16(af[i], bf[j], acc[i][j], 0, 0, 0);
    __syncthreads();
  }

#pragma unroll
  for (int i = 0; i < 4; i++) {
    const long m0 = row0 + wr * 64 + i * 16 + l4 * 4;
#pragma unroll
    for (int j = 0; j < 4; j++) {
      const long c = col0 + wc * 64 + j * 16 + l15;
      if constexpr (EPI == EPI_QKV) {
        const long which = c >> 10;
        const long cl = c & 1023;
        unsigned short* oq = (unsigned short*)out;
        if (which == 0) {
          const float bj = bias[cl];
#pragma unroll
          for (int r = 0; r < 4; r++)
            oq[(m0 + r) * 1024 + cl] = f2b((acc[i][j][r] + bj) * 0.03125f);
        } else if (which == 1) {
          const float bj = bias2[cl];
#pragma unroll
          for (int r = 0; r < 4; r++)
            (oq + 4194304)[(m0 + r) * 1024 + cl] = f2b(acc[i][j][r] + bj);
        } else {
          const float bj = bias3[cl];
          const long cc = cl >> 6, d = cl & 63;
#pragma unroll
          for (int r = 0; r < 4; r++) {
            const long m = m0 + r;
            const long nbb = m >> 10, rr = m & 1023;
            const long h = rr >> 6, rhi = rr & 63;
            const long s = rhi * 16 + cc;
            (oq + 8388608)[((nbb * 16 + h) * 64 + d) * 1024 + s] = f2b(acc[i][j][r] + bj);
          }
        }
      } else if constexpr (EPI == EPI_F32) {
        const float bj = bias[c];
        float* of = (float*)out;
#pragma unroll
        for (int r = 0; r < 4; r++) of[(m0 + r) * (long)N + c] = acc[i][j][r] + bj;
      } else if constexpr (EPI == EPI_PART) {
        unsigned short* ob = pq.p[blockIdx.z];
#pragma unroll
        for (int r = 0; r < 4; r++) ob[(m0 + r) * (long)N + c] = f2b(acc[i][j][r]);
      } else {  // EPI_GELU -> bf16
        const float bj = bias[c];
        unsigned short* ob = (unsigned short*)out;
#pragma unroll
        for (int r = 0; r < 4; r++) {
          const float t = acc[i][j][r] + bj;
          ob[(m0 + r) * (long)N + c] = f2b(0.5f * t * (1.f + erff(t * 0.70710678f)));
        }
      }
    }
  }
}

// ---------------- fused attention v8: t16 tiles, head-split softmax, 2 blocks/CU ------
// Softmax axis = heads(16). Each wave computes QK^T for 8 heads (g = w&1) on its
// 16-s slice (sw = w>>1); the other head group's partial denominator comes from a
// single 16B partner exchange through Ds. Normalization is applied BEFORE the bf16
// P write (single rounding). LDS 72KB (Qs 32K + Ps 32K + Ds 8K) + launch_bounds
// (512,4) -> 2 blocks/CU so cross-block TLP hides global K/V latency (R1 was
// 1 block/CU, latency-bound: MfmaUtil 7.6%, VALU 16%, occ 21%).
// Per iter (s-window 64): QK^T(8h) -> exp/dpart -> Ds write -> Ba -> rinv ->
// P write -> Bb -> af read -> PV(2 heads). 8 iters, grid 512 = 64 tiles x 8
// XCD-pinned combos (nb,sp). bf16 partial O per sp -> reduce_o2.
__global__ __launch_bounds__(512, 4)
void attn_kernel(const unsigned short* __restrict__ Qb,
                 const unsigned short* __restrict__ Kb,
                 const unsigned short* __restrict__ Vt,
                 unsigned short* __restrict__ P0, unsigned short* __restrict__ P1) {
  const int id = blockIdx.x;
  const int combo = id & 7;
  const int nb = combo & 3;
  const int sp = combo >> 2;
  const int tile = id >> 3;                 // 0..63 (16-row t-tiles)
  const int tid = threadIdx.x, lane = tid & 63;
  const int w = __builtin_amdgcn_readfirstlane(tid >> 6);
  const int l15 = lane & 15, l4 = lane >> 4;
  const int t0 = tile * 16;
  const int sbase = sp * 512;

  __shared__ __align__(16) unsigned short Qs[16 * 16 * 64];  // 32 KB swizzled
  __shared__ __align__(16) unsigned short Ps[16 * 16 * 64];  // 32 KB swizzled
  __shared__ __align__(16) float Ds[2 * 16 * 64];            // 8 KB swizzled

  const size_t bb = ((size_t)(nb * 16)) << 16;
  const unsigned short* qB = Qb + bb;
  const unsigned short* kB = Kb + bb;
  const unsigned short* vB = Vt + bb;

  // ---- stage Q[h][t(16)][d(64)] -> Qs (coalesced global, swizzled LDS) ----
#pragma unroll
  for (int kk = 0; kk < 4; kk++) {
    const int j = kk * 512 + tid;
    const int h = j >> 7, t = (j >> 3) & 15, d8 = j & 7;
    const int4 v = *(const int4*)(qB + ((size_t)h << 16) + (size_t)(t0 + t) * 64 + d8 * 8);
    *(int4*)((char*)Qs + h * 2048 + t * 128 + ((d8 * 16) ^ ((t & 7) << 4))) = v;
  }

  const int g   = w & 1;                    // QK^T head group (heads g*8..g*8+7)
  const int sw  = w >> 1;                   // s-slot 0..3 within 64-window
  const int h0q = g * 8;
  const int hpv = w * 2;                    // PV heads hpv, hpv+1
  const int swz = (l15 & 7) << 4;

  const int qrow = l15 * 128;
  const int qo0 = (l4 * 16) ^ swz;          // ks=0 d-bytes
  const int qo1 = (64 + l4 * 16) ^ swz;     // ks=1 d-bytes
  const int pwb = l15 * 128 + ((sw * 32 + l4 * 8) ^ swz);    // P write (b64)
  const int pr0 = l15 * 128 + ((l4 * 16) ^ swz);             // af ks=0
  const int pr1 = l15 * 128 + ((64 + l4 * 16) ^ swz);        // af ks=1
  const int dwo = l15 * 256 + ((sw * 64 + l4 * 16) ^ swz);   // Ds (b128 f32x4)

  facc4 oacc[2][4];                         // [hh][nt]
#pragma unroll
  for (int hh = 0; hh < 2; hh++)
#pragma unroll
    for (int nt = 0; nt < 4; nt++) oacc[hh][nt] = (facc4)0.f;

  __syncthreads();                          // Qs ready

  for (int it = 0; it < 8; ++it) {
    const int s0 = sbase + it * 64;         // window base
    const int sW = s0 + sw * 16;            // wave's s-slice
    // ---- QK^T: 8 heads, K from global, Q from LDS ----
    facc4 sc[8];
#pragma unroll
    for (int hi = 0; hi < 8; hi++) {
      const int h = h0q + hi;
      const unsigned short* kh = kB + ((size_t)h << 16) + (size_t)(sW + l15) * 64 + l4 * 8;
      const bfrag8 kf0 = *(const bfrag8*)kh;
      const bfrag8 kf1 = *(const bfrag8*)(kh + 32);
      const char* qh = (const char*)Qs + h * 2048 + qrow;
      const bfrag8 q0 = *(const bfrag8*)(qh + qo0);
      const bfrag8 q1 = *(const bfrag8*)(qh + qo1);
      facc4 a = __builtin_amdgcn_mfma_f32_16x16x32_bf16(kf0, q0, (facc4)0.f, 0, 0, 0);
      sc[hi] = __builtin_amdgcn_mfma_f32_16x16x32_bf16(kf1, q1, a, 0, 0, 0);
    }
    // ---- exp + 8-head partial denominator ----
    float d0 = 0.f, d1 = 0.f, d2 = 0.f, d3 = 0.f;
#pragma unroll
    for (int hi = 0; hi < 8; hi++) {
      sc[hi][0] = __expf(sc[hi][0]); d0 += sc[hi][0];
      sc[hi][1] = __expf(sc[hi][1]); d1 += sc[hi][1];
      sc[hi][2] = __expf(sc[hi][2]); d2 += sc[hi][2];
      sc[hi][3] = __expf(sc[hi][3]); d3 += sc[hi][3];
    }
    *(float4*)((char*)Ds + g * 4096 + dwo) = make_float4(d0, d1, d2, d3);
    __syncthreads();                        // Ba: partials visible
    const float4 dp = *(const float4*)((char*)Ds + (g ^ 1) * 4096 + dwo);
    const float r0 = 1.f / (d0 + dp.x);
    const float r1 = 1.f / (d1 + dp.y);
    const float r2 = 1.f / (d2 + dp.z);
    const float r3 = 1.f / (d3 + dp.w);
    // ---- normalized P -> Ps (single rounding, cvt_pk pairs) ----
#pragma unroll
    for (int hi = 0; hi < 8; hi++) {
      const float p0 = sc[hi][0] * r0, p1 = sc[hi][1] * r1;
      const float p2 = sc[hi][2] * r2, p3 = sc[hi][3] * r3;
      uint2 pk;
      asm("v_cvt_pk_bf16_f32 %0, %1, %2" : "=v"(pk.x) : "v"(p0), "v"(p1));
      asm("v_cvt_pk_bf16_f32 %0, %1, %2" : "=v"(pk.y) : "v"(p2), "v"(p3));
      *(uint2*)((char*)Ps + (h0q + hi) * 2048 + pwb) = pk;
    }
    __syncthreads();                        // Bb: P visible
    // ---- af for my 2 PV heads ----
    bfrag8 af[2][2];
#pragma unroll
    for (int hh = 0; hh < 2; hh++) {
      af[hh][0] = *(const bfrag8*)((char*)Ps + (hpv + hh) * 2048 + pr0);
      af[hh][1] = *(const bfrag8*)((char*)Ps + (hpv + hh) * 2048 + pr1);
    }
    // ---- PV: V from global (V^T layout [d][s]) ----
#pragma unroll
    for (int hh = 0; hh < 2; hh++) {
      const unsigned short* vh = vB + ((size_t)(hpv + hh) << 16) + s0 + l4 * 8;
#pragma unroll
      for (int ks = 0; ks < 2; ks++)
#pragma unroll
        for (int nt = 0; nt < 4; nt++) {
          const bfrag8 vf = *(const bfrag8*)(vh + (size_t)(nt * 16 + l15) * 1024 + ks * 32);
          oacc[hh][nt] =
              __builtin_amdgcn_mfma_f32_16x16x32_bf16(af[hh][ks], vf, oacc[hh][nt], 0, 0, 0);
        }
    }
  }

  // ---- bf16 partial O through the raw-reshape flat view ----
  unsigned short* P = sp ? P1 : P0;
#pragma unroll
  for (int hh = 0; hh < 2; hh++) {
    const size_t hb = ((size_t)nb << 20) + ((size_t)(hpv + hh) << 16);
#pragma unroll
    for (int nt = 0; nt < 4; nt++)
#pragma unroll
      for (int r = 0; r < 4; r++)
        P[hb + (size_t)(t0 + l4 * 4 + r) * 64 + nt * 16 + l15] = f2b(oacc[hh][nt][r]);
  }
}

// ---------------- reduce 2 bf16 partials -> bf16 ----------------
__global__ __launch_bounds__(256)
void reduce_o2(const unsigned short* __restrict__ P0, const unsigned short* __restrict__ P1,
               unsigned short* __restrict__ OB, int n4) {
  const int i = blockIdx.x * 256 + threadIdx.x;
  if (i < n4) {
    const ushort4 a = ((const ushort4*)P0)[i];
    const ushort4 b = ((const ushort4*)P1)[i];
    ushort4 u;
    u.x = f2b(b2f(a.x) + b2f(b.x));
    u.y = f2b(b2f(a.y) + b2f(b.y));
    u.z = f2b(b2f(a.z) + b2f(b.z));
    u.w = f2b(b2f(a.w) + b2f(b.w));
    ((ushort4*)OB)[i] = u;
  }
}

// ---- LayerNorm reducing 4 bf16 GEMM partials + bias + residual: out = LN(sum+b+res) ----
__global__ __launch_bounds__(256)
void ln_red(const unsigned short* __restrict__ P0, const unsigned short* __restrict__ P1,
            const unsigned short* __restrict__ P2, const unsigned short* __restrict__ P3,
            const float* __restrict__ bias, const float* __restrict__ resid,
            const float* __restrict__ g, const float* __restrict__ be,
            float* __restrict__ outf, unsigned short* __restrict__ outb) {
  const int row = blockIdx.x, tid = threadIdx.x;
  const size_t o4 = (size_t)row * 256 + tid;
  const ushort4 a = ((const ushort4*)P0)[o4];
  const ushort4 b = ((const ushort4*)P1)[o4];
  const ushort4 c = ((const ushort4*)P2)[o4];
  const ushort4 d = ((const ushort4*)P3)[o4];
  const float4 vb = ((const float4*)bias)[tid];
  const float4 vr = ((const float4*)resid)[o4];
  float t0 = b2f(a.x) + b2f(b.x) + b2f(c.x) + b2f(d.x) + vb.x + vr.x;
  float t1 = b2f(a.y) + b2f(b.y) + b2f(c.y) + b2f(d.y) + vb.y + vr.y;
  float t2 = b2f(a.z) + b2f(b.z) + b2f(c.z) + b2f(d.z) + vb.z + vr.z;
  float t3 = b2f(a.w) + b2f(b.w) + b2f(c.w) + b2f(d.w) + vb.w + vr.w;
  float s = t0 + t1 + t2 + t3;
  float q = t0 * t0 + t1 * t1 + t2 * t2 + t3 * t3;
#pragma unroll
  for (int off = 32; off > 0; off >>= 1) {
    s += __shfl_down(s, off, 64);
    q += __shfl_down(q, off, 64);
  }
  __shared__ float rs_[4], rq_[4];
  if ((tid & 63) == 0) { rs_[tid >> 6] = s; rq_[tid >> 6] = q; }
  __syncthreads();
  const float S = rs_[0] + rs_[1] + rs_[2] + rs_[3];
  const float Q = rq_[0] + rq_[1] + rq_[2] + rq_[3];
  const float mean = S * (1.f / 1024.f);
  const float var  = Q * (1.f / 1024.f) - mean * mean;
  const float rstd = rsqrtf(var + 1e-5f);
  const float4 vg  = ((const float4*)g)[tid];
  const float4 vbe = ((const float4*)be)[tid];
  float o0 = (t0 - mean) * rstd * vg.x + vbe.x;
  float o1 = (t1 - mean) * rstd * vg.y + vbe.y;
  float o2 = (t2 - mean) * rstd * vg.z + vbe.z;
  float o3 = (t3 - mean) * rstd * vg.w + vbe.w;
  ((float4*)(outf + (size_t)row * 1024))[tid] = make_float4(o0, o1, o2, o3);
  if (outb != nullptr) {
    ushort4 u;
    u.x = f2b(o0); u.y = f2b(o1); u.z = f2b(o2); u.w = f2b(o3);
    ((ushort4*)(outb + (size_t)row * 1024))[tid] = u;
  }
}

// ---------------- launch ----------------
extern "C" void kernel_launch(void* const* d_in, const int* in_sizes, int n_in,
                              void* d_out, int out_size, void* d_ws, size_t ws_size,
                              hipStream_t stream) {
  const float* x  = (const float*)d_in[0];
  const float* Wq = (const float*)d_in[1];
  const float* bq = (const float*)d_in[2];
  const float* Wk = (const float*)d_in[3];
  const float* bk = (const float*)d_in[4];
  const float* Wv = (const float*)d_in[5];
  const float* bv = (const float*)d_in[6];
  const float* Wo = (const float*)d_in[7];
  const float* bo = (const float*)d_in[8];
  const float* g1 = (const float*)d_in[9];
  const float* b1 = (const float*)d_in[10];
  const float* W1 = (const float*)d_in[11];
  const float* c1 = (const float*)d_in[12];
  const float* W2 = (const float*)d_in[13];
  const float* c2 = (const float*)d_in[14];
  const float* g2 = (const float*)d_in[15];
  const float* b2 = (const float*)d_in[16];
  float* out = (float*)d_out;

  char* ws = (char*)d_ws;
  unsigned short* XB  = (unsigned short*)(ws);              // 8MB  x bf16
  unsigned short* WQT = (unsigned short*)(ws + 8388608);    // 2MB
  unsigned short* WKT = (unsigned short*)(ws + 10485760);   // 2MB
  unsigned short* WVT = (unsigned short*)(ws + 12582912);   // 2MB
  unsigned short* WOT = (unsigned short*)(ws + 14680064);   // 2MB
  unsigned short* W1T = (unsigned short*)(ws + 16777216);   // 8MB
  unsigned short* W2T = (unsigned short*)(ws + 25165824);   // 8MB
  float*          X1  = (float*)(ws + 33554432);            // 16MB fp32 (LN1 out)
  unsigned short* X1B = (unsigned short*)(ws + 50331648);   // 8MB
  char* RB = ws + 58720256;                                 // 48MB union region
  unsigned short* QB  = (unsigned short*)(RB);              // 8MB
  unsigned short* KB  = (unsigned short*)(RB + 8388608);    // 8MB
  unsigned short* VT  = (unsigned short*)(RB + 16777216);   // 8MB
  unsigned short* OB  = (unsigned short*)(RB + 25165824);   // 8MB
  unsigned short* H1B = (unsigned short*)(RB);              // 32MB FFN phase (= QB..OB)
  // attn bf16 partials in dead OWO region
  unsigned short* AP0 = (unsigned short*)(RB + 33554432);
  unsigned short* AP1 = (unsigned short*)(RB + 41943040);
  // o-proj split-K partials (QB/KB/VT free after attn; XB free after QKV)
  PtrQuad OPQ = { { QB, KB, VT, XB } };
  // FFN2 split-K partials (XB,X1B free; OWO region free)
  PtrQuad FPQ = { { XB, X1B, (unsigned short*)(RB + 33554432),
                    (unsigned short*)(RB + 41943040) } };
  PtrQuad ZQ = { { nullptr, nullptr, nullptr, nullptr } };

  const dim3 tb(256);
  cvt_bf16_kernel<<<dim3(4096), tb, 0, stream>>>(x, XB, 1048576);
  transpose_cvt<<<dim3(32, 32),  tb, 0, stream>>>(Wq, WQT, 1024, 1024);
  transpose_cvt<<<dim3(32, 32),  tb, 0, stream>>>(Wk, WKT, 1024, 1024);
  transpose_cvt<<<dim3(32, 32),  tb, 0, stream>>>(Wv, WVT, 1024, 1024);
  transpose_cvt<<<dim3(32, 32),  tb, 0, stream>>>(Wo, WOT, 1024, 1024);
  transpose_cvt<<<dim3(128, 32), tb, 0, stream>>>(W1, W1T, 1024, 4096);
  transpose_cvt<<<dim3(32, 128), tb, 0, stream>>>(W2, W2T, 4096, 1024);
  // QKV (N=3072): epilogue scatters Q(scaled), K, V(per-head transposed)
  gemm_bt<EPI_QKV><<<dim3(24, 32), tb, 0, stream>>>(XB, WQT, bq, bk, bv, (void*)QB, ZQ,
                                                    4096, 3072, 1024, 1024);
  // attention v8: 512 blocks x 512 thr, (nb,sp) XCD-pinned, t16 tiles, bf16 partials
  attn_kernel<<<dim3(512), dim3(512), 0, stream>>>(QB, KB, VT, AP0, AP1);
  reduce_o2<<<dim3(4096), tb, 0, stream>>>(AP0, AP1, OB, 1048576);
  // O-proj: split-K=4 (kLen 256) -> bf16 partials; reduce+bias+residual fused in LN1
  gemm_bt<EPI_PART><<<dim3(8, 32, 4), tb, 0, stream>>>(OB, WOT, nullptr, nullptr, nullptr,
                                                       nullptr, OPQ, 4096, 1024, 256, 1024);
  ln_red<<<dim3(4096), tb, 0, stream>>>(QB, KB, VT, XB, bo, x, g1, b1, X1, X1B);
  // FFN1 + exact GELU -> bf16
  gemm_bt<EPI_GELU><<<dim3(32, 32), tb, 0, stream>>>(X1B, W1T, c1, nullptr, nullptr,
                                                     (void*)H1B, ZQ, 4096, 4096, 1024, 1024);
  // FFN2: split-K=4 (kLen 1024) -> bf16 partials; reduce+bias+residual fused in LN2
  gemm_bt<EPI_PART><<<dim3(8, 32, 4), tb, 0, stream>>>(H1B, W2T, nullptr, nullptr, nullptr,
                                                       nullptr, FPQ, 4096, 1024, 1024, 4096);
  ln_red<<<dim3(4096), tb, 0, stream>>>(FPQ.p[0], FPQ.p[1], FPQ.p[2], FPQ.p[3], c2, X1,
                                        g2, b2, out, (unsigned short*)nullptr);
}